// Round 8
// baseline (273.164 us; speedup 1.0000x reference)
//
#include <hip/hip_runtime.h>
#include <math.h>

// Problem constants (B=2, N=1024, DE=1024, H=16, DH=64 complex dims/head)
#define BB      2
#define NN      1024
#define DE_     1024
#define HH      16
#define TWO_DK  2048
#define PK      4194304     // B*H*N*128 packed elements per q/k/v stream
#define TBLR    1092        // per-head table entries: dt in [-64, 1028)

typedef float f32x4  __attribute__((ext_vector_type(4)));
typedef short bf16x8 __attribute__((ext_vector_type(8)));

__device__ __forceinline__ short f2bf(float f) {
    unsigned u = __float_as_uint(f);
    unsigned r = (u + 0x7fffu + ((u >> 16) & 1u)) >> 16;   // RNE
    return (short)r;
}

#define GLDS16(g, l) __builtin_amdgcn_global_load_lds(                        \
    (const __attribute__((address_space(1))) unsigned int*)(g),               \
    (__attribute__((address_space(3))) unsigned int*)(l), 16, 0, 0)

// ---------------------------------------------------------------------------
// prep: z=0..2 transpose Wq/Wk/Wv -> wt[n][k] bf16; z=3,bx<16 transpose Wo;
//       z=3,bx>=16 decay tables; z=4 x fp32->bf16.
// ---------------------------------------------------------------------------
__global__ __launch_bounds__(256) void prep(
    const float* __restrict__ x,
    const float* __restrict__ Wq, const float* __restrict__ Wk,
    const float* __restrict__ Wv, const float* __restrict__ Wo,
    const float* __restrict__ mu_raw, const float* __restrict__ sigma_raw,
    const float* __restrict__ eta_raw, const float* __restrict__ gamma_raw,
    short* __restrict__ xb, short* __restrict__ wt, short* __restrict__ wot,
    float4* __restrict__ tbl) {
    const int z = blockIdx.z;
    if (z == 4) {
        const int flat = blockIdx.y * 32 + blockIdx.x;
        const int i = (flat * 256 + threadIdx.x) * 8;
        float4 v0 = *(const float4*)&x[i];
        float4 v1 = *(const float4*)&x[i + 4];
        short4 o0, o1;
        o0.x = f2bf(v0.x); o0.y = f2bf(v0.y); o0.z = f2bf(v0.z); o0.w = f2bf(v0.w);
        o1.x = f2bf(v1.x); o1.y = f2bf(v1.y); o1.z = f2bf(v1.z); o1.w = f2bf(v1.w);
        *(short4*)&xb[i] = o0; *(short4*)&xb[i + 4] = o1;
        return;
    }
    if (z == 3 && blockIdx.x >= 16) {
        const int idx = blockIdx.y * 16 + (blockIdx.x - 16);
        if (idx >= 80) return;
        const int h = idx / 5, rb = idx % 5;
        const int r = rb * 256 + threadIdx.x;
        if (r >= TBLR) return;
        const float mu = 1.f / (1.f + expf(-mu_raw[h])) + 1e-4f;
        const float Ac = log1pf(expf(sigma_raw[h])) / (2.f * mu);
        const float Cc = log1pf(expf(eta_raw[h])) + log1pf(expf(gamma_raw[h]));
        const float arg = fminf(fmaxf(-mu * (float)(r - 64), -30.f), 0.f);
        const float E   = expf(arg);
        const float V   = fmaf(Ac, 1.f - E * E, Cc);
        tbl[h * TBLR + r] = make_float4(E, 1.f / V, -32.f * logf(V), 0.f);
        return;
    }
    const float* in; short* out; int R, C;
    if (z < 3) { if (blockIdx.y >= 16) return;
                 in = (z == 0) ? Wq : (z == 1) ? Wk : Wv;
                 out = wt + (size_t)z * 2097152; R = 1024; C = 2048; }
    else       { in = Wo; out = wot; R = 2048; C = 1024; }
    __shared__ float t[64][65];
    const int c0 = blockIdx.x * 64, r0 = blockIdx.y * 64;
    const int tr = threadIdx.x >> 4, tc4 = (threadIdx.x & 15) * 4;
#pragma unroll
    for (int s = 0; s < 4; ++s) {
        const int r = tr + s * 16;
        float4 v = *(const float4*)&in[(size_t)(r0 + r) * C + c0 + tc4];
        t[r][tc4] = v.x; t[r][tc4 + 1] = v.y; t[r][tc4 + 2] = v.z; t[r][tc4 + 3] = v.w;
    }
    __syncthreads();
#pragma unroll
    for (int s = 0; s < 4; ++s) {
        const int oc = tr + s * 16;
        short4 o;
        o.x = f2bf(t[tc4 + 0][oc]); o.y = f2bf(t[tc4 + 1][oc]);
        o.z = f2bf(t[tc4 + 2][oc]); o.w = f2bf(t[tc4 + 3][oc]);
        *(short4*)&out[(size_t)(c0 + oc) * R + r0 + tc4] = o;
    }
}

// ---------------------------------------------------------------------------
// QKV GEMM + fused RoPE rotation/norms. 128x128 tile, grid (16 m, 16 head, 3 z)
// = 768 blocks (3/CU). Block's 128 cols = one head's full re||im, B rows
// interleaved per 16-col subtile so acc[a][2p]/acc[a][2p+1] are the re/im pair
// of the SAME complex elem in the same lane -> in-register rotation.
// z==2: V stored transposed via 8B short4.
// ---------------------------------------------------------------------------
__global__ __launch_bounds__(256) void gemm_qkv_rot2(
    const short* __restrict__ A, const short* __restrict__ wt,
    const float* __restrict__ omega,
    short* __restrict__ qb, short* __restrict__ kb, short* __restrict__ vtb,
    float* __restrict__ qn_, float* __restrict__ kn_) {
    __shared__ __align__(16) short As[128 * 64];   // 16 KB
    __shared__ __align__(16) short Bs[128 * 64];   // 16 KB
    __shared__ float sN[2][128];
    const int tid = threadIdx.x;
    const int m0  = blockIdx.x * 128;
    const int h   = blockIdx.y;
    const short* W = wt + (size_t)blockIdx.z * 2097152;

    const short* aP[4]; const short* bP[4]; int ldsoff[4];
#pragma unroll
    for (int i = 0; i < 4; ++i) {
        const int c   = i * 256 + tid;
        const int row = c >> 3;
        const int src = ((c & 7) ^ (row & 7)) << 3;
        ldsoff[i] = c * 8;
        aP[i] = A + (size_t)(m0 + row) * 1024 + src;
        const int t_ = row >> 5, u_ = (row >> 4) & 1, dcol = t_ * 16 + (row & 15);
        bP[i] = W + (size_t)(u_ * 1024 + h * 64 + dcol) * 1024 + src;
    }

    const int lane = tid & 63, w = tid >> 6;
    const int wr = (w >> 1) * 64, hsel = w & 1, wc = hsel * 64;
    const int fr = lane & 15;
    const int fo = (lane >> 4) << 3;
    const int sw = (fr & 7) << 3;

    f32x4 acc[4][4];
#pragma unroll
    for (int a = 0; a < 4; ++a)
#pragma unroll
        for (int b = 0; b < 4; ++b) acc[a][b] = (f32x4){0.f, 0.f, 0.f, 0.f};

    for (int k0 = 0; k0 < 1024; k0 += 64) {
#pragma unroll
        for (int i = 0; i < 4; ++i) GLDS16(aP[i] + k0, &As[ldsoff[i]]);
#pragma unroll
        for (int i = 0; i < 4; ++i) GLDS16(bP[i] + k0, &Bs[ldsoff[i]]);
        __syncthreads();
#pragma unroll
        for (int ks = 0; ks < 64; ks += 32) {
            bf16x8 af[4], bf[4];
#pragma unroll
            for (int a = 0; a < 4; ++a)
                af[a] = *(const bf16x8*)&As[(wr + a * 16 + fr) * 64 + ((ks + fo) ^ sw)];
#pragma unroll
            for (int b = 0; b < 4; ++b)
                bf[b] = *(const bf16x8*)&Bs[(wc + b * 16 + fr) * 64 + ((ks + fo) ^ sw)];
#pragma unroll
            for (int a = 0; a < 4; ++a)
#pragma unroll
                for (int b = 0; b < 4; ++b)
                    acc[a][b] = __builtin_amdgcn_mfma_f32_16x16x32_bf16(
                        af[a], bf[b], acc[a][b], 0, 0, 0);
        }
        __syncthreads();
    }

    const int cq = (lane >> 4) * 4, l15 = lane & 15;
    const int bh  = (m0 >> 10) * 16 + h;
    const int nb0 = (m0 & 1023) + wr + cq;

    if (blockIdx.z == 2) {
#pragma unroll
        for (int a = 0; a < 4; ++a) {
#pragma unroll
            for (int b = 0; b < 4; ++b) {
                const int cl = wc + b * 16;
                const int dd = ((cl >> 4) & 1) * 64 + (cl >> 5) * 16 + l15;
                short4 o;
                o.x = f2bf(acc[a][b][0]); o.y = f2bf(acc[a][b][1]);
                o.z = f2bf(acc[a][b][2]); o.w = f2bf(acc[a][b][3]);
                *(short4*)&vtb[((size_t)bh * 128 + dd) * 1024 + nb0 + a * 16] = o;
            }
        }
        return;
    }
    float* nout = (blockIdx.z == 0) ? qn_ : kn_;
    short* obuf = (blockIdx.z == 0) ? qb  : kb;

#pragma unroll
    for (int a = 0; a < 4; ++a) {
        float ns[4] = {0.f, 0.f, 0.f, 0.f};
#pragma unroll
        for (int b = 0; b < 4; ++b)
#pragma unroll
            for (int r = 0; r < 4; ++r)
                ns[r] = fmaf(acc[a][b][r], acc[a][b][r], ns[r]);
#pragma unroll
        for (int m2 = 1; m2 < 16; m2 <<= 1)
#pragma unroll
            for (int r = 0; r < 4; ++r) ns[r] += __shfl_xor(ns[r], m2);
        if (l15 == 0)
#pragma unroll
            for (int r = 0; r < 4; ++r) sN[hsel][wr + a * 16 + cq + r] = ns[r];
    }
    __syncthreads();
    if (tid < 128)
        nout[(size_t)bh * 1024 + (m0 & 1023) + tid] = sN[0][tid] + sN[1][tid];

#pragma unroll
    for (int p = 0; p < 2; ++p) {
        const int d = (hsel * 2 + p) * 16 + l15;
        const float om = (d < 32) ? omega[h * 32 + d] : -omega[h * 32 + d - 32];
#pragma unroll
        for (int a = 0; a < 4; ++a) {
#pragma unroll
            for (int r = 0; r < 4; ++r) {
                const int n2 = nb0 + a * 16 + r;
                float sn, cs;
                __sincosf((float)n2 * om, &sn, &cs);
                const float re = acc[a][2 * p][r], im = acc[a][2 * p + 1][r];
                short* orow = obuf + ((size_t)bh * 1024 + n2) * 128;
                orow[d]      = f2bf(re * cs - im * sn);
                orow[64 + d] = f2bf(re * sn + im * cs);
            }
        }
    }
}

// ---------------------------------------------------------------------------
// MFMA flash attention v3: BARRIER-FREE. 4 independent waves per block; wave w
// owns Q-rows w*16..+15 of the block's 64-row i-tile. All K/V/table/kn MFMA
// operands are loaded DIRECTLY from global (16B contiguous frags, L2-resident;
// per-bh working set 512 KB). LDS holds only the per-wave P buffer (wave-
// private rows -> no __syncthreads anywhere). Waves drift freely; latency is
// hidden by 8 waves/CU with no collective drain points.
// ---------------------------------------------------------------------------
__global__ __launch_bounds__(256) void attn_mfma(
    const short* __restrict__ qr, const short* __restrict__ kr,
    const short* __restrict__ vt,
    const float* __restrict__ qn, const float* __restrict__ kn,
    const float4* __restrict__ tbl,
    const float* __restrict__ tau_p, const float* __restrict__ nu_raw,
    short* __restrict__ y) {
    __shared__ __align__(16) short Ps[64 * 72];    // 9.2 KB, wave-private rows

    const int bh = blockIdx.y;
    const int h  = bh & 15;
    const int it = (bh & 16) ? (15 - (int)blockIdx.x) : (int)blockIdx.x;
    const int i0 = it * 64;
    const int tid  = threadIdx.x;
    const int lane = tid & 63, w = tid >> 6;
    const int quad = lane >> 4, l15 = lane & 15;

    const float nu     = log1pf(expf(nu_raw[h]));
    const float coef   = -0.5f * tau_p[h] * (nu + 64.0f);
    const float inv_nu = 1.f / nu;

    const short*  Qb  = qr + (size_t)bh * NN * 128;
    const short*  Kb  = kr + (size_t)bh * NN * 128;
    const short*  Vtb = vt + (size_t)bh * 128 * NN;
    const float*  Knb = kn + (size_t)bh * NN;
    const float4* Tb  = tbl + h * TBLR + 64;       // indexed by dt

    // Q-fragments in registers: A[m=l15][k=quad*8+j]
    bf16x8 qf[4];
    const int arow = i0 + w * 16 + l15;
#pragma unroll
    for (int ks = 0; ks < 4; ++ks)
        qf[ks] = *(const bf16x8*)&Qb[(size_t)arow * 128 + ks * 32 + quad * 8];

    float mrow[4], lrow[4];
    f32x4 o[8];
#pragma unroll
    for (int r = 0; r < 4; ++r) { mrow[r] = -INFINITY; lrow[r] = 0.f; }
#pragma unroll
    for (int s = 0; s < 8; ++s) o[s] = (f32x4){0.f, 0.f, 0.f, 0.f};
    float qn4[4];
#pragma unroll
    for (int r = 0; r < 4; ++r)
        qn4[r] = qn[(size_t)bh * NN + i0 + w * 16 + quad * 4 + r];

    for (int jt = 0; jt <= it; ++jt) {
        const int j0 = jt * 64, dt0 = i0 - j0;

        // -------- S = Q @ K^T : B-frags straight from global --------
        f32x4 sAcc[4];
#pragma unroll
        for (int s = 0; s < 4; ++s) sAcc[s] = (f32x4){0.f, 0.f, 0.f, 0.f};
#pragma unroll
        for (int ks = 0; ks < 4; ++ks) {
#pragma unroll
            for (int s = 0; s < 4; ++s) {
                bf16x8 bK = *(const bf16x8*)&Kb[(size_t)(j0 + s * 16 + l15) * 128 +
                                                ks * 32 + quad * 8];
                sAcc[s] = __builtin_amdgcn_mfma_f32_16x16x32_bf16(qf[ks], bK, sAcc[s], 0, 0, 0);
            }
        }

        // -------- column norms (L2 direct) --------
        float knc[4];
#pragma unroll
        for (int s = 0; s < 4; ++s) knc[s] = Knb[j0 + s * 16 + l15];

        // -------- softmax on C-layout (row = w*16+quad*4+r, col = s*16+l15) ----
        float al[4];
#pragma unroll
        for (int r = 0; r < 4; ++r) {
            const int row = w * 16 + quad * 4 + r;
            float lg[4];
            float mx = -INFINITY;
#pragma unroll
            for (int s = 0; s < 4; ++s) {
                const int col = s * 16 + l15;
                const float4 T = Tb[dt0 + row - col];
                const float sv = sAcc[s][r];
                const float maha =
                    fmaxf(fmaf(T.x * T.x, knc[s], qn4[r]) - 2.f * T.x * sv, 0.f) * T.y;
                float v = fmaf(coef, __logf(fmaf(maha, inv_nu, 1.f)), T.z);
                if (jt == it && col > row) v = -INFINITY;
                lg[s] = v;
                mx = fmaxf(mx, v);
            }
            mx = fmaxf(mx, __shfl_xor(mx, 1));
            mx = fmaxf(mx, __shfl_xor(mx, 2));
            mx = fmaxf(mx, __shfl_xor(mx, 4));
            mx = fmaxf(mx, __shfl_xor(mx, 8));
            const float mn = fmaxf(mrow[r], mx);
            const float a_ = __expf(mrow[r] - mn);
            float rs = 0.f;
#pragma unroll
            for (int s = 0; s < 4; ++s) {
                const float pv = __expf(lg[s] - mn);
                Ps[row * 72 + s * 16 + l15] = f2bf(pv);
                rs += pv;
            }
            rs += __shfl_xor(rs, 1);
            rs += __shfl_xor(rs, 2);
            rs += __shfl_xor(rs, 4);
            rs += __shfl_xor(rs, 8);
            lrow[r] = fmaf(lrow[r], a_, rs);
            mrow[r] = mn;
            al[r] = a_;
        }
#pragma unroll
        for (int s = 0; s < 8; ++s)
#pragma unroll
            for (int r = 0; r < 4; ++r) o[s][r] *= al[r];

        // -------- O += P @ V : P from own-wave LDS rows, V straight from global
#pragma unroll
        for (int jc = 0; jc < 2; ++jc) {
            bf16x8 aP = *(const bf16x8*)&Ps[(w * 16 + l15) * 72 + jc * 32 + quad * 8];
#pragma unroll
            for (int sub = 0; sub < 8; ++sub) {
                bf16x8 bV = *(const bf16x8*)&Vtb[(size_t)(sub * 16 + l15) * 1024 +
                                                 j0 + jc * 32 + quad * 8];
                o[sub] = __builtin_amdgcn_mfma_f32_16x16x32_bf16(aP, bV, o[sub], 0, 0, 0);
            }
        }
    }

    // -------- epilogue: O/l -> bf16 packed y --------
#pragma unroll
    for (int r = 0; r < 4; ++r) {
        const float inv = 1.f / lrow[r];
        const size_t base = ((size_t)bh * NN + i0 + w * 16 + quad * 4 + r) * 128;
#pragma unroll
        for (int sub = 0; sub < 8; ++sub)
            y[base + sub * 16 + l15] = f2bf(o[sub][r] * inv);
    }
}

// ---------------------------------------------------------------------------
// Output GEMM: out[2048][1024] = y @ Wo. 64x64 tiles, grid (32,16) = 512
// blocks (2/CU), BK=64, direct f32 stores. A remapped from packed y.
// ---------------------------------------------------------------------------
__global__ __launch_bounds__(256) void gemm_out64(
    const short* __restrict__ yb, const short* __restrict__ wot,
    float* __restrict__ out) {
    __shared__ __align__(16) short As[64 * 64];
    __shared__ __align__(16) short Bs[64 * 64];
    const int tid = threadIdx.x;
    const int m0  = blockIdx.x * 64;
    const int n0  = blockIdx.y * 64;
    const int bb  = m0 >> 10;

    int aPre[2], aOff[2]; const short* bP[2];
#pragma unroll
    for (int i = 0; i < 2; ++i) {
        const int c = i * 256 + tid, row = c >> 3;
        const int src = ((c & 7) ^ (row & 7)) << 3;
        aPre[i] = ((m0 & 1023) + row) * 128 + src;
        bP[i] = wot + (size_t)(n0 + row) * 2048 + src;
        aOff[i] = c * 8;
    }

    const int lane = tid & 63, w = tid >> 6;
    const int wr = (w >> 1) * 32, wc = (w & 1) * 32;
    const int fr = lane & 15;
    const int fo = (lane >> 4) << 3;
    const int sw = (fr & 7) << 3;

    f32x4 acc[2][2];
#pragma unroll
    for (int a = 0; a < 2; ++a)
#pragma unroll
        for (int b = 0; b < 2; ++b) acc[a][b] = (f32x4){0.f, 0.f, 0.f, 0.f};

    for (int k0 = 0; k0 < 2048; k0 += 64) {
        const int hh = (k0 >> 6) & 15, im = k0 >> 10;
        const short* ab = yb + ((size_t)(bb * 16 + hh) << 17) + im * 64;
#pragma unroll
        for (int i = 0; i < 2; ++i) GLDS16(ab + aPre[i], &As[aOff[i]]);
#pragma unroll
        for (int i = 0; i < 2; ++i) GLDS16(bP[i] + k0, &Bs[aOff[i]]);
        __syncthreads();
#pragma unroll
        for (int ks = 0; ks < 64; ks += 32) {
            bf16x8 af[2], bf[2];
#pragma unroll
            for (int a = 0; a < 2; ++a)
                af[a] = *(const bf16x8*)&As[(wr + a * 16 + fr) * 64 + ((ks + fo) ^ sw)];
#pragma unroll
            for (int b = 0; b < 2; ++b)
                bf[b] = *(const bf16x8*)&Bs[(wc + b * 16 + fr) * 64 + ((ks + fo) ^ sw)];
#pragma unroll
            for (int a = 0; a < 2; ++a)
#pragma unroll
                for (int b = 0; b < 2; ++b)
                    acc[a][b] = __builtin_amdgcn_mfma_f32_16x16x32_bf16(
                        af[a], bf[b], acc[a][b], 0, 0, 0);
        }
        __syncthreads();
    }

    const int cq = (lane >> 4) * 4, l15 = lane & 15;
#pragma unroll
    for (int a = 0; a < 2; ++a)
#pragma unroll
        for (int b = 0; b < 2; ++b)
#pragma unroll
            for (int r = 0; r < 4; ++r)
                out[(size_t)(m0 + wr + a * 16 + cq + r) * 1024 +
                    (n0 + wc + b * 16 + l15)] = acc[a][b][r];
}

// ---------------------------------------------------------------------------
extern "C" void kernel_launch(void* const* d_in, const int* in_sizes, int n_in,
                              void* d_out, int out_size, void* d_ws, size_t ws_size,
                              hipStream_t stream) {
    const float* x         = (const float*)d_in[0];
    const float* Wq        = (const float*)d_in[1];
    const float* Wk        = (const float*)d_in[2];
    const float* Wv        = (const float*)d_in[3];
    const float* Wo        = (const float*)d_in[4];
    const float* omega     = (const float*)d_in[5];
    const float* mu_raw    = (const float*)d_in[6];
    const float* sigma_raw = (const float*)d_in[7];
    const float* eta_raw   = (const float*)d_in[8];
    const float* gamma_raw = (const float*)d_in[9];
    const float* tau       = (const float*)d_in[10];
    const float* nu_raw    = (const float*)d_in[11];
    float* out = (float*)d_out;

    short*  qb  = (short*)d_ws;
    short*  kb  = qb + PK;
    short*  vtb = kb + PK;
    float*  qn  = (float*)(vtb + PK);
    float*  kn  = qn + 32768;
    float4* tbl = (float4*)(kn + 32768);
    short*  wot = (short*)(tbl + HH * TBLR);
    short*  wt  = wot + 2097152;
    short*  xb  = wt + 3 * 2097152;
    short*  yb  = wt;                               // alias (wt dead after qkv)

    prep<<<dim3(32, 32, 5), 256, 0, stream>>>(
        x, Wq, Wk, Wv, Wo, mu_raw, sigma_raw, eta_raw, gamma_raw,
        xb, wt, wot, tbl);
    gemm_qkv_rot2<<<dim3(16, 16, 3), 256, 0, stream>>>(
        xb, wt, omega, qb, kb, vtb, qn, kn);
    attn_mfma<<<dim3(16, 32), 256, 0, stream>>>(
        qb, kb, vtb, qn, kn, tbl, tau, nu_raw, yb);
    gemm_out64<<<dim3(32, 16), 256, 0, stream>>>(yb, wot, out);
}

// Round 10
// 219.906 us; speedup vs baseline: 1.2422x; 1.2422x over previous
//
#include <hip/hip_runtime.h>
#include <math.h>

// Problem constants (B=2, N=1024, DE=1024, H=16, DH=64 complex dims/head)
#define BB      2
#define NN      1024
#define DE_     1024
#define HH      16
#define TWO_DK  2048
#define PK      4194304     // B*H*N*128 packed elements per q/k/v stream
#define TBLR    1092        // per-head table entries: dt in [-64, 1028)

typedef float f32x4  __attribute__((ext_vector_type(4)));
typedef short bf16x8 __attribute__((ext_vector_type(8)));

__device__ __forceinline__ short f2bf(float f) {
    unsigned u = __float_as_uint(f);
    unsigned r = (u + 0x7fffu + ((u >> 16) & 1u)) >> 16;   // RNE
    return (short)r;
}

#define GLDS16(g, l) __builtin_amdgcn_global_load_lds(                        \
    (const __attribute__((address_space(1))) unsigned int*)(g),               \
    (__attribute__((address_space(3))) unsigned int*)(l), 16, 0, 0)
#define GLDS4(g, l) __builtin_amdgcn_global_load_lds(                         \
    (const __attribute__((address_space(1))) unsigned int*)(g),               \
    (__attribute__((address_space(3))) unsigned int*)(l), 4, 0, 0)

// ---------------------------------------------------------------------------
// prep: z=0..2 transpose Wq/Wk/Wv -> wt[n][k] bf16; z=3,bx<16 transpose Wo;
//       z=3,bx>=16 decay tables; z=4 x fp32->bf16.
// ---------------------------------------------------------------------------
__global__ __launch_bounds__(256) void prep(
    const float* __restrict__ x,
    const float* __restrict__ Wq, const float* __restrict__ Wk,
    const float* __restrict__ Wv, const float* __restrict__ Wo,
    const float* __restrict__ mu_raw, const float* __restrict__ sigma_raw,
    const float* __restrict__ eta_raw, const float* __restrict__ gamma_raw,
    short* __restrict__ xb, short* __restrict__ wt, short* __restrict__ wot,
    float4* __restrict__ tbl) {
    const int z = blockIdx.z;
    if (z == 4) {
        const int flat = blockIdx.y * 32 + blockIdx.x;
        const int i = (flat * 256 + threadIdx.x) * 8;
        float4 v0 = *(const float4*)&x[i];
        float4 v1 = *(const float4*)&x[i + 4];
        short4 o0, o1;
        o0.x = f2bf(v0.x); o0.y = f2bf(v0.y); o0.z = f2bf(v0.z); o0.w = f2bf(v0.w);
        o1.x = f2bf(v1.x); o1.y = f2bf(v1.y); o1.z = f2bf(v1.z); o1.w = f2bf(v1.w);
        *(short4*)&xb[i] = o0; *(short4*)&xb[i + 4] = o1;
        return;
    }
    if (z == 3 && blockIdx.x >= 16) {
        const int idx = blockIdx.y * 16 + (blockIdx.x - 16);
        if (idx >= 80) return;
        const int h = idx / 5, rb = idx % 5;
        const int r = rb * 256 + threadIdx.x;
        if (r >= TBLR) return;
        const float mu = 1.f / (1.f + expf(-mu_raw[h])) + 1e-4f;
        const float Ac = log1pf(expf(sigma_raw[h])) / (2.f * mu);
        const float Cc = log1pf(expf(eta_raw[h])) + log1pf(expf(gamma_raw[h]));
        const float arg = fminf(fmaxf(-mu * (float)(r - 64), -30.f), 0.f);
        const float E   = expf(arg);
        const float V   = fmaf(Ac, 1.f - E * E, Cc);
        tbl[h * TBLR + r] = make_float4(E, 1.f / V, -32.f * logf(V), 0.f);
        return;
    }
    const float* in; short* out; int R, C;
    if (z < 3) { if (blockIdx.y >= 16) return;
                 in = (z == 0) ? Wq : (z == 1) ? Wk : Wv;
                 out = wt + (size_t)z * 2097152; R = 1024; C = 2048; }
    else       { in = Wo; out = wot; R = 2048; C = 1024; }
    __shared__ float t[64][65];
    const int c0 = blockIdx.x * 64, r0 = blockIdx.y * 64;
    const int tr = threadIdx.x >> 4, tc4 = (threadIdx.x & 15) * 4;
#pragma unroll
    for (int s = 0; s < 4; ++s) {
        const int r = tr + s * 16;
        float4 v = *(const float4*)&in[(size_t)(r0 + r) * C + c0 + tc4];
        t[r][tc4] = v.x; t[r][tc4 + 1] = v.y; t[r][tc4 + 2] = v.z; t[r][tc4 + 3] = v.w;
    }
    __syncthreads();
#pragma unroll
    for (int s = 0; s < 4; ++s) {
        const int oc = tr + s * 16;
        short4 o;
        o.x = f2bf(t[tc4 + 0][oc]); o.y = f2bf(t[tc4 + 1][oc]);
        o.z = f2bf(t[tc4 + 2][oc]); o.w = f2bf(t[tc4 + 3][oc]);
        *(short4*)&out[(size_t)(c0 + oc) * R + r0 + tc4] = o;
    }
}

// ---------------------------------------------------------------------------
// QKV GEMM + fused RoPE rotation/norms (R7-proven). 128x128 tile, grid
// (16 m, 16 head, 3 z) = 768 blocks. z==2: V stored transposed via 8B short4.
// ---------------------------------------------------------------------------
__global__ __launch_bounds__(256) void gemm_qkv_rot2(
    const short* __restrict__ A, const short* __restrict__ wt,
    const float* __restrict__ omega,
    short* __restrict__ qb, short* __restrict__ kb, short* __restrict__ vtb,
    float* __restrict__ qn_, float* __restrict__ kn_) {
    __shared__ __align__(16) short As[128 * 64];
    __shared__ __align__(16) short Bs[128 * 64];
    __shared__ float sN[2][128];
    const int tid = threadIdx.x;
    const int m0  = blockIdx.x * 128;
    const int h   = blockIdx.y;
    const short* W = wt + (size_t)blockIdx.z * 2097152;

    const short* aP[4]; const short* bP[4]; int ldsoff[4];
#pragma unroll
    for (int i = 0; i < 4; ++i) {
        const int c   = i * 256 + tid;
        const int row = c >> 3;
        const int src = ((c & 7) ^ (row & 7)) << 3;
        ldsoff[i] = c * 8;
        aP[i] = A + (size_t)(m0 + row) * 1024 + src;
        const int t_ = row >> 5, u_ = (row >> 4) & 1, dcol = t_ * 16 + (row & 15);
        bP[i] = W + (size_t)(u_ * 1024 + h * 64 + dcol) * 1024 + src;
    }

    const int lane = tid & 63, w = tid >> 6;
    const int wr = (w >> 1) * 64, hsel = w & 1, wc = hsel * 64;
    const int fr = lane & 15;
    const int fo = (lane >> 4) << 3;
    const int sw = (fr & 7) << 3;

    f32x4 acc[4][4];
#pragma unroll
    for (int a = 0; a < 4; ++a)
#pragma unroll
        for (int b = 0; b < 4; ++b) acc[a][b] = (f32x4){0.f, 0.f, 0.f, 0.f};

    for (int k0 = 0; k0 < 1024; k0 += 64) {
#pragma unroll
        for (int i = 0; i < 4; ++i) GLDS16(aP[i] + k0, &As[ldsoff[i]]);
#pragma unroll
        for (int i = 0; i < 4; ++i) GLDS16(bP[i] + k0, &Bs[ldsoff[i]]);
        __syncthreads();
#pragma unroll
        for (int ks = 0; ks < 64; ks += 32) {
            bf16x8 af[4], bf[4];
#pragma unroll
            for (int a = 0; a < 4; ++a)
                af[a] = *(const bf16x8*)&As[(wr + a * 16 + fr) * 64 + ((ks + fo) ^ sw)];
#pragma unroll
            for (int b = 0; b < 4; ++b)
                bf[b] = *(const bf16x8*)&Bs[(wc + b * 16 + fr) * 64 + ((ks + fo) ^ sw)];
#pragma unroll
            for (int a = 0; a < 4; ++a)
#pragma unroll
                for (int b = 0; b < 4; ++b)
                    acc[a][b] = __builtin_amdgcn_mfma_f32_16x16x32_bf16(
                        af[a], bf[b], acc[a][b], 0, 0, 0);
        }
        __syncthreads();
    }

    const int cq = (lane >> 4) * 4, l15 = lane & 15;
    const int bh  = (m0 >> 10) * 16 + h;
    const int nb0 = (m0 & 1023) + wr + cq;

    if (blockIdx.z == 2) {
#pragma unroll
        for (int a = 0; a < 4; ++a) {
#pragma unroll
            for (int b = 0; b < 4; ++b) {
                const int cl = wc + b * 16;
                const int dd = ((cl >> 4) & 1) * 64 + (cl >> 5) * 16 + l15;
                short4 o;
                o.x = f2bf(acc[a][b][0]); o.y = f2bf(acc[a][b][1]);
                o.z = f2bf(acc[a][b][2]); o.w = f2bf(acc[a][b][3]);
                *(short4*)&vtb[((size_t)bh * 128 + dd) * 1024 + nb0 + a * 16] = o;
            }
        }
        return;
    }
    float* nout = (blockIdx.z == 0) ? qn_ : kn_;
    short* obuf = (blockIdx.z == 0) ? qb  : kb;

#pragma unroll
    for (int a = 0; a < 4; ++a) {
        float ns[4] = {0.f, 0.f, 0.f, 0.f};
#pragma unroll
        for (int b = 0; b < 4; ++b)
#pragma unroll
            for (int r = 0; r < 4; ++r)
                ns[r] = fmaf(acc[a][b][r], acc[a][b][r], ns[r]);
#pragma unroll
        for (int m2 = 1; m2 < 16; m2 <<= 1)
#pragma unroll
            for (int r = 0; r < 4; ++r) ns[r] += __shfl_xor(ns[r], m2);
        if (l15 == 0)
#pragma unroll
            for (int r = 0; r < 4; ++r) sN[hsel][wr + a * 16 + cq + r] = ns[r];
    }
    __syncthreads();
    if (tid < 128)
        nout[(size_t)bh * 1024 + (m0 & 1023) + tid] = sN[0][tid] + sN[1][tid];

#pragma unroll
    for (int p = 0; p < 2; ++p) {
        const int d = (hsel * 2 + p) * 16 + l15;
        const float om = (d < 32) ? omega[h * 32 + d] : -omega[h * 32 + d - 32];
#pragma unroll
        for (int a = 0; a < 4; ++a) {
#pragma unroll
            for (int r = 0; r < 4; ++r) {
                const int n2 = nb0 + a * 16 + r;
                float sn, cs;
                __sincosf((float)n2 * om, &sn, &cs);
                const float re = acc[a][2 * p][r], im = acc[a][2 * p + 1][r];
                short* orow = obuf + ((size_t)bh * 1024 + n2) * 128;
                orow[d]      = f2bf(re * cs - im * sn);
                orow[64 + d] = f2bf(re * sn + im * cs);
            }
        }
    }
}

// ---------------------------------------------------------------------------
// MFMA flash attention (R7 pipelined double-buffer) + XCD-aware swizzle:
// 1-D grid 512; xcd = bx&7, bh = xcd*4 + (j&3), it mirrored by bh parity.
// All 16 i-blocks of one bh land on ONE XCD -> 2 MB K/V set L2-resident.
// Table index FIXED back to row-col+63 (STAGE window already includes dt0).
// ---------------------------------------------------------------------------
__global__ __launch_bounds__(256) void attn_mfma(
    const short* __restrict__ qr, const short* __restrict__ kr,
    const short* __restrict__ vt,
    const float* __restrict__ qn, const float* __restrict__ kn,
    const float4* __restrict__ tbl,
    const float* __restrict__ tau_p, const float* __restrict__ nu_raw,
    short* __restrict__ y) {
    __shared__ __align__(16) short Ks[2][64 * 128];
    __shared__ __align__(16) short Vs[2][128 * 64];
    __shared__ __align__(16) short Ps[64 * 72];
    __shared__ __align__(16) float4 sT[2][128];
    __shared__ float sKn[2][64];

    const int bx  = blockIdx.x;
    const int xcd = bx & 7;
    const int j   = bx >> 3;                  // 0..63 per XCD
    const int bh  = xcd * 4 + (j & 3);        // 4 bh per XCD
    const int h   = bh & 15;
    const int itr = j >> 2;                   // 0..15
    const int it  = (bh & 1) ? (15 - itr) : itr;   // balance within XCD
    const int i0  = it * 64;
    const int tid  = threadIdx.x;
    const int lane = tid & 63, w = tid >> 6;
    const int quad = lane >> 4, l15 = lane & 15;

    const float nu     = log1pf(expf(nu_raw[h]));
    const float coef   = -0.5f * tau_p[h] * (nu + 64.0f);
    const float inv_nu = 1.f / nu;

    const short* Qb  = qr + (size_t)bh * NN * 128;
    const short* Kb  = kr + (size_t)bh * NN * 128;
    const short* Vtb = vt + (size_t)bh * 128 * NN;

#define STAGE(JT, P) do {                                                     \
        const int j0_ = (JT) * 64, dt0_ = i0 - j0_;                           \
        _Pragma("unroll")                                                     \
        for (int i_ = 0; i_ < 4; ++i_) {                                      \
            const int c_ = i_ * 256 + tid, row_ = c_ >> 4;                    \
            const int src_ = ((c_ & 15) ^ (row_ & 7)) * 8;                    \
            GLDS16(Kb + (size_t)(j0_ + row_) * 128 + src_, &Ks[P][c_ * 8]);   \
        }                                                                     \
        _Pragma("unroll")                                                     \
        for (int i_ = 0; i_ < 4; ++i_) {                                      \
            const int c_ = i_ * 256 + tid, d_ = c_ >> 3;                      \
            const int src_ = ((c_ & 7) ^ (d_ & 7)) * 8;                       \
            GLDS16(Vtb + (size_t)d_ * NN + j0_ + src_, &Vs[P][c_ * 8]);       \
        }                                                                     \
        if (w == 0) {                                                         \
            GLDS16(tbl + h * TBLR + 1 + dt0_ + lane, &sT[P][lane]);           \
            GLDS16(tbl + h * TBLR + 65 + dt0_ + lane, &sT[P][64 + lane]);     \
        } else if (w == 1) {                                                  \
            GLDS4(kn + (size_t)bh * NN + j0_ + lane, &sKn[P][lane]);          \
        }                                                                     \
    } while (0)

    bf16x8 qf[4];
    const int arow = i0 + w * 16 + l15;
#pragma unroll
    for (int ks = 0; ks < 4; ++ks)
        qf[ks] = *(const bf16x8*)&Qb[(size_t)arow * 128 + ks * 32 + quad * 8];

    float mrow[4], lrow[4];
    f32x4 o[8];
#pragma unroll
    for (int r = 0; r < 4; ++r) { mrow[r] = -INFINITY; lrow[r] = 0.f; }
#pragma unroll
    for (int s = 0; s < 8; ++s) o[s] = (f32x4){0.f, 0.f, 0.f, 0.f};
    float qn4[4];
#pragma unroll
    for (int r = 0; r < 4; ++r)
        qn4[r] = qn[(size_t)bh * NN + i0 + w * 16 + quad * 4 + r];

    STAGE(0, 0);
    __syncthreads();

    for (int jt = 0; jt <= it; ++jt) {
        const int p = jt & 1;
        if (jt < it) STAGE(jt + 1, 1 - p);   // async prefetch; drained at barrier

        f32x4 sAcc[4];
#pragma unroll
        for (int s = 0; s < 4; ++s) sAcc[s] = (f32x4){0.f, 0.f, 0.f, 0.f};
#pragma unroll
        for (int ks = 0; ks < 4; ++ks) {
#pragma unroll
            for (int s = 0; s < 4; ++s) {
                const int brow = s * 16 + l15;
                bf16x8 bK = *(const bf16x8*)&Ks[p][brow * 128 +
                                                  (((ks * 4 + quad) ^ (brow & 7)) * 8)];
                sAcc[s] = __builtin_amdgcn_mfma_f32_16x16x32_bf16(qf[ks], bK, sAcc[s], 0, 0, 0);
            }
        }

        float al[4];
#pragma unroll
        for (int r = 0; r < 4; ++r) {
            const int row = w * 16 + quad * 4 + r;
            float lg[4];
            float mx = -INFINITY;
#pragma unroll
            for (int s = 0; s < 4; ++s) {
                const int col = s * 16 + l15;
                const float4 T = sT[p][row - col + 63];   // window already at dt0
                const float sv = sAcc[s][r];
                const float maha =
                    fmaxf(fmaf(T.x * T.x, sKn[p][col], qn4[r]) - 2.f * T.x * sv, 0.f) * T.y;
                float v = fmaf(coef, __logf(fmaf(maha, inv_nu, 1.f)), T.z);
                if (jt == it && col > row) v = -INFINITY;
                lg[s] = v;
                mx = fmaxf(mx, v);
            }
            mx = fmaxf(mx, __shfl_xor(mx, 1));
            mx = fmaxf(mx, __shfl_xor(mx, 2));
            mx = fmaxf(mx, __shfl_xor(mx, 4));
            mx = fmaxf(mx, __shfl_xor(mx, 8));
            const float mn = fmaxf(mrow[r], mx);
            const float a_ = __expf(mrow[r] - mn);
            float rs = 0.f;
#pragma unroll
            for (int s = 0; s < 4; ++s) {
                const float pv = __expf(lg[s] - mn);
                Ps[row * 72 + s * 16 + l15] = f2bf(pv);
                rs += pv;
            }
            rs += __shfl_xor(rs, 1);
            rs += __shfl_xor(rs, 2);
            rs += __shfl_xor(rs, 4);
            rs += __shfl_xor(rs, 8);
            lrow[r] = fmaf(lrow[r], a_, rs);
            mrow[r] = mn;
            al[r] = a_;
        }
#pragma unroll
        for (int s = 0; s < 8; ++s)
#pragma unroll
            for (int r = 0; r < 4; ++r) o[s][r] *= al[r];

#pragma unroll
        for (int jc = 0; jc < 2; ++jc) {
            bf16x8 aP = *(const bf16x8*)&Ps[(w * 16 + l15) * 72 + jc * 32 + quad * 8];
#pragma unroll
            for (int sub = 0; sub < 8; ++sub) {
                const int d = sub * 16 + l15;
                bf16x8 bV = *(const bf16x8*)&Vs[p][d * 64 + (((jc * 4 + quad) ^ (d & 7)) * 8)];
                o[sub] = __builtin_amdgcn_mfma_f32_16x16x32_bf16(aP, bV, o[sub], 0, 0, 0);
            }
        }
        if (jt < it) __syncthreads();
    }
#undef STAGE

#pragma unroll
    for (int r = 0; r < 4; ++r) {
        const float inv = 1.f / lrow[r];
        const size_t base = ((size_t)bh * NN + i0 + w * 16 + quad * 4 + r) * 128;
#pragma unroll
        for (int sub = 0; sub < 8; ++sub)
            y[base + sub * 16 + l15] = f2bf(o[sub][r] * inv);
    }
}

// ---------------------------------------------------------------------------
// Output GEMM: out[2048][1024] = y @ Wo. 64x64 tiles, grid (32,16) = 512
// blocks (2/CU), BK=64, direct f32 stores. A remapped from packed y.
// ---------------------------------------------------------------------------
__global__ __launch_bounds__(256) void gemm_out64(
    const short* __restrict__ yb, const short* __restrict__ wot,
    float* __restrict__ out) {
    __shared__ __align__(16) short As[64 * 64];
    __shared__ __align__(16) short Bs[64 * 64];
    const int tid = threadIdx.x;
    const int m0  = blockIdx.x * 64;
    const int n0  = blockIdx.y * 64;
    const int bb  = m0 >> 10;

    int aPre[2], aOff[2]; const short* bP[2];
#pragma unroll
    for (int i = 0; i < 2; ++i) {
        const int c = i * 256 + tid, row = c >> 3;
        const int src = ((c & 7) ^ (row & 7)) << 3;
        aPre[i] = ((m0 & 1023) + row) * 128 + src;
        bP[i] = wot + (size_t)(n0 + row) * 2048 + src;
        aOff[i] = c * 8;
    }

    const int lane = tid & 63, w = tid >> 6;
    const int wr = (w >> 1) * 32, wc = (w & 1) * 32;
    const int fr = lane & 15;
    const int fo = (lane >> 4) << 3;
    const int sw = (fr & 7) << 3;

    f32x4 acc[2][2];
#pragma unroll
    for (int a = 0; a < 2; ++a)
#pragma unroll
        for (int b = 0; b < 2; ++b) acc[a][b] = (f32x4){0.f, 0.f, 0.f, 0.f};

    for (int k0 = 0; k0 < 2048; k0 += 64) {
        const int hh = (k0 >> 6) & 15, im = k0 >> 10;
        const short* ab = yb + ((size_t)(bb * 16 + hh) << 17) + im * 64;
#pragma unroll
        for (int i = 0; i < 2; ++i) GLDS16(ab + aPre[i], &As[aOff[i]]);
#pragma unroll
        for (int i = 0; i < 2; ++i) GLDS16(bP[i] + k0, &Bs[aOff[i]]);
        __syncthreads();
#pragma unroll
        for (int ks = 0; ks < 64; ks += 32) {
            bf16x8 af[2], bf[2];
#pragma unroll
            for (int a = 0; a < 2; ++a)
                af[a] = *(const bf16x8*)&As[(wr + a * 16 + fr) * 64 + ((ks + fo) ^ sw)];
#pragma unroll
            for (int b = 0; b < 2; ++b)
                bf[b] = *(const bf16x8*)&Bs[(wc + b * 16 + fr) * 64 + ((ks + fo) ^ sw)];
#pragma unroll
            for (int a = 0; a < 2; ++a)
#pragma unroll
                for (int b = 0; b < 2; ++b)
                    acc[a][b] = __builtin_amdgcn_mfma_f32_16x16x32_bf16(
                        af[a], bf[b], acc[a][b], 0, 0, 0);
        }
        __syncthreads();
    }

    const int cq = (lane >> 4) * 4, l15 = lane & 15;
#pragma unroll
    for (int a = 0; a < 2; ++a)
#pragma unroll
        for (int b = 0; b < 2; ++b)
#pragma unroll
            for (int r = 0; r < 4; ++r)
                out[(size_t)(m0 + wr + a * 16 + cq + r) * 1024 +
                    (n0 + wc + b * 16 + l15)] = acc[a][b][r];
}

// ---------------------------------------------------------------------------
extern "C" void kernel_launch(void* const* d_in, const int* in_sizes, int n_in,
                              void* d_out, int out_size, void* d_ws, size_t ws_size,
                              hipStream_t stream) {
    const float* x         = (const float*)d_in[0];
    const float* Wq        = (const float*)d_in[1];
    const float* Wk        = (const float*)d_in[2];
    const float* Wv        = (const float*)d_in[3];
    const float* Wo        = (const float*)d_in[4];
    const float* omega     = (const float*)d_in[5];
    const float* mu_raw    = (const float*)d_in[6];
    const float* sigma_raw = (const float*)d_in[7];
    const float* eta_raw   = (const float*)d_in[8];
    const float* gamma_raw = (const float*)d_in[9];
    const float* tau       = (const float*)d_in[10];
    const float* nu_raw    = (const float*)d_in[11];
    float* out = (float*)d_out;

    short*  qb  = (short*)d_ws;
    short*  kb  = qb + PK;
    short*  vtb = kb + PK;
    float*  qn  = (float*)(vtb + PK);
    float*  kn  = qn + 32768;
    float4* tbl = (float4*)(kn + 32768);
    short*  wot = (short*)(tbl + HH * TBLR);
    short*  wt  = wot + 2097152;
    short*  xb  = wt + 3 * 2097152;
    short*  yb  = wt;                               // alias (wt dead after qkv)

    prep<<<dim3(32, 32, 5), 256, 0, stream>>>(
        x, Wq, Wk, Wv, Wo, mu_raw, sigma_raw, eta_raw, gamma_raw,
        xb, wt, wot, tbl);
    gemm_qkv_rot2<<<dim3(16, 16, 3), 256, 0, stream>>>(
        xb, wt, omega, qb, kb, vtb, qn, kn);
    attn_mfma<<<dim3(512), 256, 0, stream>>>(
        qb, kb, vtb, qn, kn, tbl, tau, nu_raw, yb);
    gemm_out64<<<dim3(32, 16), 256, 0, stream>>>(yb, wot, out);
}

// Round 11
// 218.375 us; speedup vs baseline: 1.2509x; 1.0070x over previous
//
#include <hip/hip_runtime.h>
#include <math.h>

// Problem constants (B=2, N=1024, DE=1024, H=16, DH=64 complex dims/head)
#define BB      2
#define NN      1024
#define DE_     1024
#define HH      16
#define TWO_DK  2048
#define PK      4194304     // B*H*N*128 packed elements per q/k/v stream
#define TBLR    1092        // per-head table entries: dt in [-64, 1028)

typedef float f32x4  __attribute__((ext_vector_type(4)));
typedef short bf16x8 __attribute__((ext_vector_type(8)));

__device__ __forceinline__ short f2bf(float f) {
    unsigned u = __float_as_uint(f);
    unsigned r = (u + 0x7fffu + ((u >> 16) & 1u)) >> 16;   // RNE
    return (short)r;
}

#define GLDS16(g, l) __builtin_amdgcn_global_load_lds(                        \
    (const __attribute__((address_space(1))) unsigned int*)(g),               \
    (__attribute__((address_space(3))) unsigned int*)(l), 16, 0, 0)
#define GLDS4(g, l) __builtin_amdgcn_global_load_lds(                         \
    (const __attribute__((address_space(1))) unsigned int*)(g),               \
    (__attribute__((address_space(3))) unsigned int*)(l), 4, 0, 0)

// ---------------------------------------------------------------------------
// prep: z=0..2 transpose Wq/Wk/Wv -> wt[n][k] bf16; z=3,bx<16 transpose Wo;
//       z=3,bx>=16 decay tables; z=4 x fp32->bf16.
// ---------------------------------------------------------------------------
__global__ __launch_bounds__(256) void prep(
    const float* __restrict__ x,
    const float* __restrict__ Wq, const float* __restrict__ Wk,
    const float* __restrict__ Wv, const float* __restrict__ Wo,
    const float* __restrict__ mu_raw, const float* __restrict__ sigma_raw,
    const float* __restrict__ eta_raw, const float* __restrict__ gamma_raw,
    short* __restrict__ xb, short* __restrict__ wt, short* __restrict__ wot,
    float4* __restrict__ tbl) {
    const int z = blockIdx.z;
    if (z == 4) {
        const int flat = blockIdx.y * 32 + blockIdx.x;
        const int i = (flat * 256 + threadIdx.x) * 8;
        float4 v0 = *(const float4*)&x[i];
        float4 v1 = *(const float4*)&x[i + 4];
        short4 o0, o1;
        o0.x = f2bf(v0.x); o0.y = f2bf(v0.y); o0.z = f2bf(v0.z); o0.w = f2bf(v0.w);
        o1.x = f2bf(v1.x); o1.y = f2bf(v1.y); o1.z = f2bf(v1.z); o1.w = f2bf(v1.w);
        *(short4*)&xb[i] = o0; *(short4*)&xb[i + 4] = o1;
        return;
    }
    if (z == 3 && blockIdx.x >= 16) {
        const int idx = blockIdx.y * 16 + (blockIdx.x - 16);
        if (idx >= 80) return;
        const int h = idx / 5, rb = idx % 5;
        const int r = rb * 256 + threadIdx.x;
        if (r >= TBLR) return;
        const float mu = 1.f / (1.f + expf(-mu_raw[h])) + 1e-4f;
        const float Ac = log1pf(expf(sigma_raw[h])) / (2.f * mu);
        const float Cc = log1pf(expf(eta_raw[h])) + log1pf(expf(gamma_raw[h]));
        const float arg = fminf(fmaxf(-mu * (float)(r - 64), -30.f), 0.f);
        const float E   = expf(arg);
        const float V   = fmaf(Ac, 1.f - E * E, Cc);
        tbl[h * TBLR + r] = make_float4(E, 1.f / V, -32.f * logf(V), 0.f);
        return;
    }
    const float* in; short* out; int R, C;
    if (z < 3) { if (blockIdx.y >= 16) return;
                 in = (z == 0) ? Wq : (z == 1) ? Wk : Wv;
                 out = wt + (size_t)z * 2097152; R = 1024; C = 2048; }
    else       { in = Wo; out = wot; R = 2048; C = 1024; }
    __shared__ float t[64][65];
    const int c0 = blockIdx.x * 64, r0 = blockIdx.y * 64;
    const int tr = threadIdx.x >> 4, tc4 = (threadIdx.x & 15) * 4;
#pragma unroll
    for (int s = 0; s < 4; ++s) {
        const int r = tr + s * 16;
        float4 v = *(const float4*)&in[(size_t)(r0 + r) * C + c0 + tc4];
        t[r][tc4] = v.x; t[r][tc4 + 1] = v.y; t[r][tc4 + 2] = v.z; t[r][tc4 + 3] = v.w;
    }
    __syncthreads();
#pragma unroll
    for (int s = 0; s < 4; ++s) {
        const int oc = tr + s * 16;
        short4 o;
        o.x = f2bf(t[tc4 + 0][oc]); o.y = f2bf(t[tc4 + 1][oc]);
        o.z = f2bf(t[tc4 + 2][oc]); o.w = f2bf(t[tc4 + 3][oc]);
        *(short4*)&out[(size_t)(c0 + oc) * R + r0 + tc4] = o;
    }
}

// ---------------------------------------------------------------------------
// QKV GEMM + fused RoPE rotation/norms (R7-proven). 128x128 tile, grid
// (16 m, 16 head, 3 z) = 768 blocks. z==2: V stored transposed via 8B short4.
// ---------------------------------------------------------------------------
__global__ __launch_bounds__(256) void gemm_qkv_rot2(
    const short* __restrict__ A, const short* __restrict__ wt,
    const float* __restrict__ omega,
    short* __restrict__ qb, short* __restrict__ kb, short* __restrict__ vtb,
    float* __restrict__ qn_, float* __restrict__ kn_) {
    __shared__ __align__(16) short As[128 * 64];
    __shared__ __align__(16) short Bs[128 * 64];
    __shared__ float sN[2][128];
    const int tid = threadIdx.x;
    const int m0  = blockIdx.x * 128;
    const int h   = blockIdx.y;
    const short* W = wt + (size_t)blockIdx.z * 2097152;

    const short* aP[4]; const short* bP[4]; int ldsoff[4];
#pragma unroll
    for (int i = 0; i < 4; ++i) {
        const int c   = i * 256 + tid;
        const int row = c >> 3;
        const int src = ((c & 7) ^ (row & 7)) << 3;
        ldsoff[i] = c * 8;
        aP[i] = A + (size_t)(m0 + row) * 1024 + src;
        const int t_ = row >> 5, u_ = (row >> 4) & 1, dcol = t_ * 16 + (row & 15);
        bP[i] = W + (size_t)(u_ * 1024 + h * 64 + dcol) * 1024 + src;
    }

    const int lane = tid & 63, w = tid >> 6;
    const int wr = (w >> 1) * 64, hsel = w & 1, wc = hsel * 64;
    const int fr = lane & 15;
    const int fo = (lane >> 4) << 3;
    const int sw = (fr & 7) << 3;

    f32x4 acc[4][4];
#pragma unroll
    for (int a = 0; a < 4; ++a)
#pragma unroll
        for (int b = 0; b < 4; ++b) acc[a][b] = (f32x4){0.f, 0.f, 0.f, 0.f};

    for (int k0 = 0; k0 < 1024; k0 += 64) {
#pragma unroll
        for (int i = 0; i < 4; ++i) GLDS16(aP[i] + k0, &As[ldsoff[i]]);
#pragma unroll
        for (int i = 0; i < 4; ++i) GLDS16(bP[i] + k0, &Bs[ldsoff[i]]);
        __syncthreads();
#pragma unroll
        for (int ks = 0; ks < 64; ks += 32) {
            bf16x8 af[4], bf[4];
#pragma unroll
            for (int a = 0; a < 4; ++a)
                af[a] = *(const bf16x8*)&As[(wr + a * 16 + fr) * 64 + ((ks + fo) ^ sw)];
#pragma unroll
            for (int b = 0; b < 4; ++b)
                bf[b] = *(const bf16x8*)&Bs[(wc + b * 16 + fr) * 64 + ((ks + fo) ^ sw)];
#pragma unroll
            for (int a = 0; a < 4; ++a)
#pragma unroll
                for (int b = 0; b < 4; ++b)
                    acc[a][b] = __builtin_amdgcn_mfma_f32_16x16x32_bf16(
                        af[a], bf[b], acc[a][b], 0, 0, 0);
        }
        __syncthreads();
    }

    const int cq = (lane >> 4) * 4, l15 = lane & 15;
    const int bh  = (m0 >> 10) * 16 + h;
    const int nb0 = (m0 & 1023) + wr + cq;

    if (blockIdx.z == 2) {
#pragma unroll
        for (int a = 0; a < 4; ++a) {
#pragma unroll
            for (int b = 0; b < 4; ++b) {
                const int cl = wc + b * 16;
                const int dd = ((cl >> 4) & 1) * 64 + (cl >> 5) * 16 + l15;
                short4 o;
                o.x = f2bf(acc[a][b][0]); o.y = f2bf(acc[a][b][1]);
                o.z = f2bf(acc[a][b][2]); o.w = f2bf(acc[a][b][3]);
                *(short4*)&vtb[((size_t)bh * 128 + dd) * 1024 + nb0 + a * 16] = o;
            }
        }
        return;
    }
    float* nout = (blockIdx.z == 0) ? qn_ : kn_;
    short* obuf = (blockIdx.z == 0) ? qb  : kb;

#pragma unroll
    for (int a = 0; a < 4; ++a) {
        float ns[4] = {0.f, 0.f, 0.f, 0.f};
#pragma unroll
        for (int b = 0; b < 4; ++b)
#pragma unroll
            for (int r = 0; r < 4; ++r)
                ns[r] = fmaf(acc[a][b][r], acc[a][b][r], ns[r]);
#pragma unroll
        for (int m2 = 1; m2 < 16; m2 <<= 1)
#pragma unroll
            for (int r = 0; r < 4; ++r) ns[r] += __shfl_xor(ns[r], m2);
        if (l15 == 0)
#pragma unroll
            for (int r = 0; r < 4; ++r) sN[hsel][wr + a * 16 + cq + r] = ns[r];
    }
    __syncthreads();
    if (tid < 128)
        nout[(size_t)bh * 1024 + (m0 & 1023) + tid] = sN[0][tid] + sN[1][tid];

#pragma unroll
    for (int p = 0; p < 2; ++p) {
        const int d = (hsel * 2 + p) * 16 + l15;
        const float om = (d < 32) ? omega[h * 32 + d] : -omega[h * 32 + d - 32];
#pragma unroll
        for (int a = 0; a < 4; ++a) {
#pragma unroll
            for (int r = 0; r < 4; ++r) {
                const int n2 = nb0 + a * 16 + r;
                float sn, cs;
                __sincosf((float)n2 * om, &sn, &cs);
                const float re = acc[a][2 * p][r], im = acc[a][2 * p + 1][r];
                short* orow = obuf + ((size_t)bh * 1024 + n2) * 128;
                orow[d]      = f2bf(re * cs - im * sn);
                orow[64 + d] = f2bf(re * sn + im * cs);
            }
        }
    }
}

// ---------------------------------------------------------------------------
// MFMA flash attention (pipelined double-buffer) + XCD-local bh mapping +
// BALANCED per-CU pairing: it = (itr<8) ? itr : 23-itr, so the two co-resident
// blocks of each CU (j and j+32, same bh) sum to exactly 17 tiles.
// R10 confirmed FETCH 57->12.8 MB from the XCD mapping; R10's regression was
// the (itr, itr+8) pairing giving per-CU work in [10,24] tiles.
// ---------------------------------------------------------------------------
__global__ __launch_bounds__(256) void attn_mfma(
    const short* __restrict__ qr, const short* __restrict__ kr,
    const short* __restrict__ vt,
    const float* __restrict__ qn, const float* __restrict__ kn,
    const float4* __restrict__ tbl,
    const float* __restrict__ tau_p, const float* __restrict__ nu_raw,
    short* __restrict__ y) {
    __shared__ __align__(16) short Ks[2][64 * 128];
    __shared__ __align__(16) short Vs[2][128 * 64];
    __shared__ __align__(16) short Ps[64 * 72];
    __shared__ __align__(16) float4 sT[2][128];
    __shared__ float sKn[2][64];

    const int bx  = blockIdx.x;
    const int xcd = bx & 7;
    const int j   = bx >> 3;                  // 0..63 per XCD
    const int bh  = xcd * 4 + (j & 3);        // 4 bh per XCD
    const int h   = bh & 15;
    const int itr = j >> 2;                   // 0..15
    const int it  = (itr < 8) ? itr : 23 - itr;   // CU pair (itr,itr+8): 17 tiles
    const int i0  = it * 64;
    const int tid  = threadIdx.x;
    const int lane = tid & 63, w = tid >> 6;
    const int quad = lane >> 4, l15 = lane & 15;

    const float nu     = log1pf(expf(nu_raw[h]));
    const float coef   = -0.5f * tau_p[h] * (nu + 64.0f);
    const float inv_nu = 1.f / nu;

    const short* Qb  = qr + (size_t)bh * NN * 128;
    const short* Kb  = kr + (size_t)bh * NN * 128;
    const short* Vtb = vt + (size_t)bh * 128 * NN;

#define STAGE(JT, P) do {                                                     \
        const int j0_ = (JT) * 64, dt0_ = i0 - j0_;                           \
        _Pragma("unroll")                                                     \
        for (int i_ = 0; i_ < 4; ++i_) {                                      \
            const int c_ = i_ * 256 + tid, row_ = c_ >> 4;                    \
            const int src_ = ((c_ & 15) ^ (row_ & 7)) * 8;                    \
            GLDS16(Kb + (size_t)(j0_ + row_) * 128 + src_, &Ks[P][c_ * 8]);   \
        }                                                                     \
        _Pragma("unroll")                                                     \
        for (int i_ = 0; i_ < 4; ++i_) {                                      \
            const int c_ = i_ * 256 + tid, d_ = c_ >> 3;                      \
            const int src_ = ((c_ & 7) ^ (d_ & 7)) * 8;                       \
            GLDS16(Vtb + (size_t)d_ * NN + j0_ + src_, &Vs[P][c_ * 8]);       \
        }                                                                     \
        if (w == 0) {                                                         \
            GLDS16(tbl + h * TBLR + 1 + dt0_ + lane, &sT[P][lane]);           \
            GLDS16(tbl + h * TBLR + 65 + dt0_ + lane, &sT[P][64 + lane]);     \
        } else if (w == 1) {                                                  \
            GLDS4(kn + (size_t)bh * NN + j0_ + lane, &sKn[P][lane]);          \
        }                                                                     \
    } while (0)

    bf16x8 qf[4];
    const int arow = i0 + w * 16 + l15;
#pragma unroll
    for (int ks = 0; ks < 4; ++ks)
        qf[ks] = *(const bf16x8*)&Qb[(size_t)arow * 128 + ks * 32 + quad * 8];

    float mrow[4], lrow[4];
    f32x4 o[8];
#pragma unroll
    for (int r = 0; r < 4; ++r) { mrow[r] = -INFINITY; lrow[r] = 0.f; }
#pragma unroll
    for (int s = 0; s < 8; ++s) o[s] = (f32x4){0.f, 0.f, 0.f, 0.f};
    float qn4[4];
#pragma unroll
    for (int r = 0; r < 4; ++r)
        qn4[r] = qn[(size_t)bh * NN + i0 + w * 16 + quad * 4 + r];

    STAGE(0, 0);
    __syncthreads();

    for (int jt = 0; jt <= it; ++jt) {
        const int p = jt & 1;
        if (jt < it) STAGE(jt + 1, 1 - p);   // async prefetch; drained at barrier

        f32x4 sAcc[4];
#pragma unroll
        for (int s = 0; s < 4; ++s) sAcc[s] = (f32x4){0.f, 0.f, 0.f, 0.f};
#pragma unroll
        for (int ks = 0; ks < 4; ++ks) {
#pragma unroll
            for (int s = 0; s < 4; ++s) {
                const int brow = s * 16 + l15;
                bf16x8 bK = *(const bf16x8*)&Ks[p][brow * 128 +
                                                  (((ks * 4 + quad) ^ (brow & 7)) * 8)];
                sAcc[s] = __builtin_amdgcn_mfma_f32_16x16x32_bf16(qf[ks], bK, sAcc[s], 0, 0, 0);
            }
        }

        float al[4];
#pragma unroll
        for (int r = 0; r < 4; ++r) {
            const int row = w * 16 + quad * 4 + r;
            float lg[4];
            float mx = -INFINITY;
#pragma unroll
            for (int s = 0; s < 4; ++s) {
                const int col = s * 16 + l15;
                const float4 T = sT[p][row - col + 63];   // window already at dt0
                const float sv = sAcc[s][r];
                const float maha =
                    fmaxf(fmaf(T.x * T.x, sKn[p][col], qn4[r]) - 2.f * T.x * sv, 0.f) * T.y;
                float v = fmaf(coef, __logf(fmaf(maha, inv_nu, 1.f)), T.z);
                if (jt == it && col > row) v = -INFINITY;
                lg[s] = v;
                mx = fmaxf(mx, v);
            }
            mx = fmaxf(mx, __shfl_xor(mx, 1));
            mx = fmaxf(mx, __shfl_xor(mx, 2));
            mx = fmaxf(mx, __shfl_xor(mx, 4));
            mx = fmaxf(mx, __shfl_xor(mx, 8));
            const float mn = fmaxf(mrow[r], mx);
            const float a_ = __expf(mrow[r] - mn);
            float rs = 0.f;
#pragma unroll
            for (int s = 0; s < 4; ++s) {
                const float pv = __expf(lg[s] - mn);
                Ps[row * 72 + s * 16 + l15] = f2bf(pv);
                rs += pv;
            }
            rs += __shfl_xor(rs, 1);
            rs += __shfl_xor(rs, 2);
            rs += __shfl_xor(rs, 4);
            rs += __shfl_xor(rs, 8);
            lrow[r] = fmaf(lrow[r], a_, rs);
            mrow[r] = mn;
            al[r] = a_;
        }
#pragma unroll
        for (int s = 0; s < 8; ++s)
#pragma unroll
            for (int r = 0; r < 4; ++r) o[s][r] *= al[r];

#pragma unroll
        for (int jc = 0; jc < 2; ++jc) {
            bf16x8 aP = *(const bf16x8*)&Ps[(w * 16 + l15) * 72 + jc * 32 + quad * 8];
#pragma unroll
            for (int sub = 0; sub < 8; ++sub) {
                const int d = sub * 16 + l15;
                bf16x8 bV = *(const bf16x8*)&Vs[p][d * 64 + (((jc * 4 + quad) ^ (d & 7)) * 8)];
                o[sub] = __builtin_amdgcn_mfma_f32_16x16x32_bf16(aP, bV, o[sub], 0, 0, 0);
            }
        }
        if (jt < it) __syncthreads();
    }
#undef STAGE

#pragma unroll
    for (int r = 0; r < 4; ++r) {
        const float inv = 1.f / lrow[r];
        const size_t base = ((size_t)bh * NN + i0 + w * 16 + quad * 4 + r) * 128;
#pragma unroll
        for (int sub = 0; sub < 8; ++sub)
            y[base + sub * 16 + l15] = f2bf(o[sub][r] * inv);
    }
}

// ---------------------------------------------------------------------------
// Output GEMM: out[2048][1024] = y @ Wo. 64x64 tiles, grid (32,16) = 512
// blocks (2/CU), BK=64, direct f32 stores. A remapped from packed y.
// ---------------------------------------------------------------------------
__global__ __launch_bounds__(256) void gemm_out64(
    const short* __restrict__ yb, const short* __restrict__ wot,
    float* __restrict__ out) {
    __shared__ __align__(16) short As[64 * 64];
    __shared__ __align__(16) short Bs[64 * 64];
    const int tid = threadIdx.x;
    const int m0  = blockIdx.x * 64;
    const int n0  = blockIdx.y * 64;
    const int bb  = m0 >> 10;

    int aPre[2], aOff[2]; const short* bP[2];
#pragma unroll
    for (int i = 0; i < 2; ++i) {
        const int c = i * 256 + tid, row = c >> 3;
        const int src = ((c & 7) ^ (row & 7)) << 3;
        aPre[i] = ((m0 & 1023) + row) * 128 + src;
        bP[i] = wot + (size_t)(n0 + row) * 2048 + src;
        aOff[i] = c * 8;
    }

    const int lane = tid & 63, w = tid >> 6;
    const int wr = (w >> 1) * 32, wc = (w & 1) * 32;
    const int fr = lane & 15;
    const int fo = (lane >> 4) << 3;
    const int sw = (fr & 7) << 3;

    f32x4 acc[2][2];
#pragma unroll
    for (int a = 0; a < 2; ++a)
#pragma unroll
        for (int b = 0; b < 2; ++b) acc[a][b] = (f32x4){0.f, 0.f, 0.f, 0.f};

    for (int k0 = 0; k0 < 2048; k0 += 64) {
        const int hh = (k0 >> 6) & 15, im = k0 >> 10;
        const short* ab = yb + ((size_t)(bb * 16 + hh) << 17) + im * 64;
#pragma unroll
        for (int i = 0; i < 2; ++i) GLDS16(ab + aPre[i], &As[aOff[i]]);
#pragma unroll
        for (int i = 0; i < 2; ++i) GLDS16(bP[i] + k0, &Bs[aOff[i]]);
        __syncthreads();
#pragma unroll
        for (int ks = 0; ks < 64; ks += 32) {
            bf16x8 af[2], bf[2];
#pragma unroll
            for (int a = 0; a < 2; ++a)
                af[a] = *(const bf16x8*)&As[(wr + a * 16 + fr) * 64 + ((ks + fo) ^ sw)];
#pragma unroll
            for (int b = 0; b < 2; ++b)
                bf[b] = *(const bf16x8*)&Bs[(wc + b * 16 + fr) * 64 + ((ks + fo) ^ sw)];
#pragma unroll
            for (int a = 0; a < 2; ++a)
#pragma unroll
                for (int b = 0; b < 2; ++b)
                    acc[a][b] = __builtin_amdgcn_mfma_f32_16x16x32_bf16(
                        af[a], bf[b], acc[a][b], 0, 0, 0);
        }
        __syncthreads();
    }

    const int cq = (lane >> 4) * 4, l15 = lane & 15;
#pragma unroll
    for (int a = 0; a < 2; ++a)
#pragma unroll
        for (int b = 0; b < 2; ++b)
#pragma unroll
            for (int r = 0; r < 4; ++r)
                out[(size_t)(m0 + wr + a * 16 + cq + r) * 1024 +
                    (n0 + wc + b * 16 + l15)] = acc[a][b][r];
}

// ---------------------------------------------------------------------------
extern "C" void kernel_launch(void* const* d_in, const int* in_sizes, int n_in,
                              void* d_out, int out_size, void* d_ws, size_t ws_size,
                              hipStream_t stream) {
    const float* x         = (const float*)d_in[0];
    const float* Wq        = (const float*)d_in[1];
    const float* Wk        = (const float*)d_in[2];
    const float* Wv        = (const float*)d_in[3];
    const float* Wo        = (const float*)d_in[4];
    const float* omega     = (const float*)d_in[5];
    const float* mu_raw    = (const float*)d_in[6];
    const float* sigma_raw = (const float*)d_in[7];
    const float* eta_raw   = (const float*)d_in[8];
    const float* gamma_raw = (const float*)d_in[9];
    const float* tau       = (const float*)d_in[10];
    const float* nu_raw    = (const float*)d_in[11];
    float* out = (float*)d_out;

    short*  qb  = (short*)d_ws;
    short*  kb  = qb + PK;
    short*  vtb = kb + PK;
    float*  qn  = (float*)(vtb + PK);
    float*  kn  = qn + 32768;
    float4* tbl = (float4*)(kn + 32768);
    short*  wot = (short*)(tbl + HH * TBLR);
    short*  wt  = wot + 2097152;
    short*  xb  = wt + 3 * 2097152;
    short*  yb  = wt;                               // alias (wt dead after qkv)

    prep<<<dim3(32, 32, 5), 256, 0, stream>>>(
        x, Wq, Wk, Wv, Wo, mu_raw, sigma_raw, eta_raw, gamma_raw,
        xb, wt, wot, tbl);
    gemm_qkv_rot2<<<dim3(16, 16, 3), 256, 0, stream>>>(
        xb, wt, omega, qb, kb, vtb, qn, kn);
    attn_mfma<<<dim3(512), 256, 0, stream>>>(
        qb, kb, vtb, qn, kn, tbl, tau, nu_raw, yb);
    gemm_out64<<<dim3(32, 16), 256, 0, stream>>>(yb, wot, out);
}